// Round 17
// baseline (112.970 us; speedup 1.0000x reference)
//
#include <hip/hip_runtime.h>

// Sizes (fixed for this problem)
constexpr int B  = 2,  CIN = 2,  H = 64, W = 64, T = 350;
constexpr int C1 = 8;                       // conv1 out channels
constexpr int TO = 700, HO = 128, WO = 64;
constexpr int HW = H * W;                   // 4096

#define DEC 0.05000000074505806f            // (float)(1.0 - 0.95)

// ---------------------------------------------------------------------------
// Kernel 0: transpose x [B,2,H,W,T] -> xT [B,2,T,H,W] so conv reads coalesce.
// ---------------------------------------------------------------------------
__global__ void __launch_bounds__(256) transpose_kernel(
    const float* __restrict__ x, float* __restrict__ xT) {
  __shared__ float tile[64][65];
  int bid   = blockIdx.x;
  int tTile = bid % 6;            // 6 tiles of 64 cover T=350
  int slice = bid / 6;            // (b*2+ci)*64 + h
  int h  = slice % H;
  int bc = slice / H;             // b*2+ci
  int t0 = tTile * 64;
  int tx = threadIdx.x & 63;
  int tz = threadIdx.x >> 6;      // 0..3

  const float* src = x + ((long)bc * H + h) * (long)(W * T);
#pragma unroll
  for (int i = 0; i < 16; ++i) {
    int w = tz * 16 + i;
    int t = t0 + tx;
    tile[w][tx] = (t < T) ? src[(long)w * T + t] : 0.0f;
  }
  __syncthreads();
  float* dst = xT + ((long)bc * T) * HW + h * 64;
#pragma unroll
  for (int i = 0; i < 16; ++i) {
    int tl = tz * 16 + i;
    int t  = t0 + tl;
    if (t < T) dst[(long)t * HW + tx] = tile[tx][tl];
  }
}

// ---------------------------------------------------------------------------
// async global->LDS, 16 bytes per lane (wave-uniform LDS base + lane*16)
// ---------------------------------------------------------------------------
__device__ __forceinline__ void gload_lds16(const float* g, float* l) {
  __builtin_amdgcn_global_load_lds(
      (const __attribute__((address_space(1))) unsigned int*)g,
      (__attribute__((address_space(3))) unsigned int*)l, 16, 0, 0);
}

// ---------------------------------------------------------------------------
// Kernel A: conv1(5x5 over T,H) + bias + relu + LIF1 + delta -> d8 int8
// d8 layout: [b][t][hw][ci]. 2-co-per-thread (r14 structure).
// CHANGE r17: 8 chunks of 45 (was 4 of 90) -> grid 512 = 2 blocks/CU
// co-resident (2 x 74KB LDS = 148KB <= 160KB; 16 waves x 128 VGPR = full
// 2048-reg pool). Serial path 105 -> 60 steps.
// ---------------------------------------------------------------------------
__global__ void __launch_bounds__(512) convlif_kernel(
    const float* __restrict__ xT, const float* __restrict__ w1,
    const float* __restrict__ b1, signed char* __restrict__ d8) {
  __shared__ float buf[2][128 * 64];                    // 2 x 32 KiB
  __shared__ __align__(16) unsigned char st[10][1024];  // 10 KiB spikes
  const int tid = threadIdx.x;
  const int bid = blockIdx.x;
  const int chunk = bid & 7;
  const int rest  = bid >> 3;
  const int h2 = rest & 31;                 // h-pair index
  const int b  = rest >> 5;
  const int h0 = h2 * 2;
  const int w  = tid & 63;
  const int hs = (tid >> 6) & 1;            // wave h-sub
  const int cp = tid >> 7;                  // co-pair 0..3
  const int h  = h0 + hs;
  const int wid = tid >> 6;                 // wave id 0..7

  // chunk c of 8 (len 45; last 35): stored [45c, te); 15-step warm-up.
  const int tstore = chunk * 45;
  const int ts     = chunk ? tstore - 15 : 0;     // multiple of 5
  const int te     = tstore + 45 < T ? tstore + 45 : T;
  const int nsup   = (te - ts + 9) / 10;

  // Weights for co0=2cp, co1=2cp+1 (VGPR); zero taps with h+dh-2 OOB.
  float wt[2][2][5][5];
#pragma unroll
  for (int ci = 0; ci < 2; ++ci)
#pragma unroll
    for (int dh = 0; dh < 5; ++dh) {
      int hh = h + dh - 2;
      bool hv = (hh >= 0) && (hh < H);
#pragma unroll
      for (int dt = 0; dt < 5; ++dt) {
        wt[0][ci][dt][dh] = hv ? w1[(((cp*2+0) * 2 + ci) * 5 + dt) * 5 + dh] : 0.0f;
        wt[1][ci][dt][dh] = hv ? w1[(((cp*2+1) * 2 + ci) * 5 + dt) * 5 + dh] : 0.0f;
      }
    }
  float bias0 = b1[cp*2], bias1 = b1[cp*2+1];

  // Staging descriptors: 4 issues x 32 rows; row r = j*12 + ci*6 + dhh,
  // dhh in [0,6) covering h rows h0-2..h0+3 (union of both h-subs).
  int cdesc[4];
#pragma unroll
  for (int i = 0; i < 4; ++i) {
    int r = (tid >> 4) + 32 * i;
    if (r > 119) r = 119;                   // clamp SOURCE; dest rows <=127 ok
    int j   = r / 12;
    int rem = r - j * 12;
    int ci  = rem / 6;
    int dhh = rem - ci * 6;
    int hh = h0 + dhh - 2;
    int hc = hh < 0 ? 0 : (hh > H - 1 ? H - 1 : hh);
    cdesc[i] = (((b * 2 + ci) * T) * HW + hc * 64 + (tid & 15) * 4) | (j << 27);
  }

  // Prologue: stage buf[0] (taus ts+3 .. ts+12).
#pragma unroll
  for (int i = 0; i < 4; ++i) {
    int tau = ts + 3 + (cdesc[i] >> 27);
    if (tau > T - 1) tau = T - 1;
    gload_lds16(xT + (long)(cdesc[i] & 0x07ffffff) + (long)tau * HW,
                &buf[0][(i * 32 + wid * 4) * 64]);
  }

  // Window init (taus ts-2..ts+2) from global; slot = tau % 5 (ts%5==0).
  float win[2][5][5];
#pragma unroll
  for (int ci = 0; ci < 2; ++ci)
#pragma unroll
    for (int dh = 0; dh < 5; ++dh) {
      int hh = h + dh - 2;
      int hc = hh < 0 ? 0 : (hh > H - 1 ? H - 1 : hh);
      const float* bp = xT + ((long)((b * 2 + ci) * T)) * HW + hc * 64 + w;
      win[ci][dh][3] = (ts >= 2) ? bp[(long)(ts - 2) * HW] : 0.0f;
      win[ci][dh][4] = (ts >= 1) ? bp[(long)(ts - 1) * HW] : 0.0f;
      win[ci][dh][0] = bp[(long)(ts + 0) * HW];
      win[ci][dh][1] = bp[(long)(ts + 1) * HW];
      win[ci][dh][2] = bp[(long)(ts + 2) * HW];
    }

  asm volatile("s_waitcnt vmcnt(0)" ::: "memory");
  __builtin_amdgcn_s_barrier();
  asm volatile("" ::: "memory");

  signed char* const d8row = d8 + ((long)(b * T)) * (HW * C1) + h0 * 512;
  const int stw = ((hs * 64 + w) * 8 + cp * 2) >> 1;   // ushort index in row

  float y0 = 0.0f, y1 = 0.0f, sp0 = 0.0f, sp1 = 0.0f;
  for (int k = 0; k < nsup; ++k) {
    // barrier1: publish st writes of superstep k-1; next-buf readers done.
    asm volatile("s_waitcnt lgkmcnt(0)" ::: "memory");
    __builtin_amdgcn_s_barrier();
    asm volatile("" ::: "memory");

    // Flush superstep k-1 spikes (stores issued BEFORE staging loads so
    // vmcnt(4) drains them along with buffer-k loads).
    if (k > 0) {
      int tb = ts + 10 * (k - 1);
#pragma unroll
      for (int i = 0; i < 2; ++i) {
        int slot = tid + i * 512;
        if (slot < 640) {
          int u = slot >> 6;
          int c = (slot & 63) * 16;
          int t = tb + u;
          if (t >= tstore && t < te) {
            uint4 v = *reinterpret_cast<const uint4*>(&st[u][c]);
            *reinterpret_cast<uint4*>(d8row + (long)t * (HW * C1) + c) = v;
          }
        }
      }
    }

    if (k + 1 < nsup) {
      int bs = ts + 3 + 10 * (k + 1);
      float* nb = &buf[(k + 1) & 1][0];
#pragma unroll
      for (int i = 0; i < 4; ++i) {
        int tau = bs + (cdesc[i] >> 27);
        if (tau > T - 1) tau = T - 1;
        gload_lds16(xT + (long)(cdesc[i] & 0x07ffffff) + (long)tau * HW,
                    nb + (i * 32 + wid * 4) * 64);
      }
      asm volatile("s_waitcnt vmcnt(4)" ::: "memory");  // buf[k&1]+stores done
    } else {
      asm volatile("s_waitcnt vmcnt(0)" ::: "memory");
    }
    asm volatile("s_waitcnt lgkmcnt(0)" ::: "memory");
    __builtin_amdgcn_s_barrier();           // barrier2: buf[k&1] ready, st free
    asm volatile("" ::: "memory");

    float* lb = &buf[k & 1][0];
    {
      // zero rows whose tau >= T (final supersteps of last chunk only)
      int bufstart = ts + 3 + 10 * k;
      int rz0 = (T - bufstart) * 12;
      if (rz0 < 120) {
        if (rz0 < 0) rz0 = 0;
        for (int r = rz0 + wid; r < 120; r += 8) lb[r * 64 + w] = 0.0f;
        asm volatile("s_waitcnt lgkmcnt(0)" ::: "memory");
        __builtin_amdgcn_s_barrier();
        asm volatile("" ::: "memory");
      }
    }

    const int t0s = ts + 10 * k;
    for (int jj = 0; jj < 2; ++jj) {
#pragma unroll
      for (int u = 0; u < 5; ++u) {
        const int j5 = jj * 5;
        int t = t0s + j5 + u;
        float a0q0 = 0.f, a0q1 = 0.f, a0q2 = 0.f, a0q3 = 0.f;
        float a1q0 = 0.f, a1q1 = 0.f, a1q2 = 0.f, a1q3 = 0.f;
#pragma unroll
        for (int ci = 0; ci < 2; ++ci)
#pragma unroll
          for (int dt = 0; dt < 5; ++dt) {
            const int slot = (u + dt + 3) % 5;
#pragma unroll
            for (int dh = 0; dh < 5; ++dh) {
              const int q = (ci * 25 + dt * 5 + dh) & 3;
              float tap = win[ci][dh][slot];
              float p0 = tap * wt[0][ci][dt][dh];
              float p1 = tap * wt[1][ci][dt][dh];
              if (q == 0)      { a0q0 += p0; a1q0 += p1; }
              else if (q == 1) { a0q1 += p0; a1q1 += p1; }
              else if (q == 2) { a0q2 += p0; a1q2 += p1; }
              else             { a0q3 += p0; a1q3 += p1; }
            }
          }
        float a0 = fmaxf(((a0q0 + a0q1) + (a0q2 + a0q3)) + bias0, 0.0f);
        float a1 = fmaxf(((a1q0 + a1q1) + (a1q2 + a1q3)) + bias1, 0.0f);
        y0 = fmaf(DEC, y0, a0);
        y1 = fmaf(DEC, y1, a1);
        float s0 = (y0 >= 1.0f) ? 1.0f : 0.0f;
        float s1 = (y1 >= 1.0f) ? 1.0f : 0.0f;
        int d0 = (int)(s0 - sp0) & 0xff;
        int d1 = (int)(s1 - sp1) & 0xff;
        unsigned short val = (unsigned short)(d0 | (d1 << 8));
        if (t == 0) val = 0;
        reinterpret_cast<unsigned short*>(&st[j5 + u][0])[stw] = val;
        sp0 = s0; sp1 = s1;
        y0 = (s0 != 0.0f) ? 0.0f : y0;
        y1 = (s1 != 0.0f) ? 0.0f : y1;
        // slide: tau = t+3 at row ((j5+u)*12 + ci*6 + dh + hs)
        const int slot2 = (u + 3) % 5;
#pragma unroll
        for (int ci = 0; ci < 2; ++ci)
#pragma unroll
          for (int dh = 0; dh < 5; ++dh)
            win[ci][dh][slot2] =
                lb[((j5 + u) * 12 + ci * 6 + dh + hs) * 64 + w];
      }
    }
  }

  // Epilogue flush: last superstep's spikes.
  asm volatile("s_waitcnt lgkmcnt(0)" ::: "memory");
  __builtin_amdgcn_s_barrier();
  asm volatile("" ::: "memory");
  {
    int tb = ts + 10 * (nsup - 1);
#pragma unroll
    for (int i = 0; i < 2; ++i) {
      int slot = tid + i * 512;
      if (slot < 640) {
        int u = slot >> 6;
        int c = (slot & 63) * 16;
        int t = tb + u;
        if (t >= tstore && t < te) {
          uint4 v = *reinterpret_cast<const uint4*>(&st[u][c]);
          *reinterpret_cast<uint4*>(d8row + (long)t * (HW * C1) + c) = v;
        }
      }
    }
  }
}

// ---------------------------------------------------------------------------
// Kernel B: deconv(2x2,s2) + bias + relu + conv2(1x1) + LIF2 -> out
// d8 [b][t][hw][ci]: one 8B uint2 load per pair-step.
// CHANGE r17: prefetch depth 2 (three loads in flight) -- covers the full
// ~200-400cyc L2 latency of the stride-32KB loads instead of ~100cyc.
// 25 chunks x 4-wave blocks (1600 blocks); per-wave SB slices.
// ---------------------------------------------------------------------------
__global__ void __launch_bounds__(256) stage2_kernel(
    const signed char* __restrict__ d8, const float* __restrict__ dw,
    const float* __restrict__ db, const float* __restrict__ cw,
    const float* __restrict__ cb, float* __restrict__ out) {
  __shared__ float SB[4][2][64][17];        // 34 KiB, one slice per wave
  int bid   = blockIdx.x;
  int chunk = bid % 25;                     // 25 chunks over T'=700
  int rest  = bid / 25;
  int hp4 = rest & 31;                      // h' quad index (HO/4 = 32)
  int b   = rest >> 5;
  int wavei = threadIdx.x >> 6;             // 0..3
  int wp    = threadIdx.x & 63;             // w'
  int hp = hp4 * 4 + wavei;                 // this wave's h'

  int h  = hp >> 1;
  int kh = 1 - (hp & 1);

  float dwk0[2][8], dwk1[2][8];
#pragma unroll
  for (int c = 0; c < 2; ++c)
#pragma unroll
    for (int ci = 0; ci < 8; ++ci) {
      dwk0[c][ci] = dw[((c * 8 + ci) * 2 + 0) * 2 + kh];
      dwk1[c][ci] = dw[((c * 8 + ci) * 2 + 1) * 2 + kh];
    }
  float db0 = db[0], db1 = db[1];
  float cw00 = cw[0], cw01 = cw[1], cw10 = cw[2], cw11 = cw[3];
  float cb0 = cb[0], cb1 = cb[1];

  int t0 = chunk * 28;
  int t1 = t0 + 28;                         // 25*28 = 700 exactly
  int tw = (t0 - 16 > 0) ? t0 - 16 : 0;     // 16-step LIF2 warm-up (even)

  const signed char* dbase = d8 + (((long)b * T) * HW + h * 64 + wp) * C1;
  const long tstride = (long)HW * C1;       // bytes per t
  float* outb = out + ((long)b * 2 * HO) * (long)(WO * TO);

  // Prefetch pipeline, depth 2 (q0 = current, q1/q2 in flight).
  auto ldq = [&](int tp) -> uint2 {
    int t = (tp < t1) ? (tp >> 1) : ((t1 - 1) >> 1);
    return *reinterpret_cast<const uint2*>(dbase + (long)t * tstride);
  };
  uint2 q0 = ldq(tw);
  uint2 q1 = ldq(tw + 2);

  float y0 = 0.0f, y1 = 0.0f;
  for (int tp = tw; tp < t1; tp += 2) {
    uint2 q2 = ldq(tp + 4);

    float dv[8];
#pragma unroll
    for (int ci = 0; ci < 4; ++ci) {
      dv[ci]     = (float)(signed char)((q0.x >> (8 * ci)) & 0xff);
      dv[ci + 4] = (float)(signed char)((q0.y >> (8 * ci)) & 0xff);
    }

#pragma unroll
    for (int par = 0; par < 2; ++par) {     // par=0: tp (kt=1), par=1: tp+1 (kt=0)
      int tpp = tp + par;
      float v0 = db0, v1 = db1;
      if (par == 0) {
#pragma unroll
        for (int ci = 0; ci < 8; ++ci) {
          v0 = fmaf(dv[ci], dwk1[0][ci], v0);
          v1 = fmaf(dv[ci], dwk1[1][ci], v1);
        }
      } else {
#pragma unroll
        for (int ci = 0; ci < 8; ++ci) {
          v0 = fmaf(dv[ci], dwk0[0][ci], v0);
          v1 = fmaf(dv[ci], dwk0[1][ci], v1);
        }
      }
      v0 = fmaxf(v0, 0.0f);
      v1 = fmaxf(v1, 0.0f);
      float u0 = fmaf(cw00, v0, fmaf(cw01, v1, cb0));
      float u1 = fmaf(cw10, v0, fmaf(cw11, v1, cb1));
      y0 = fmaf(DEC, y0, u0);
      y1 = fmaf(DEC, y1, u1);
      float s0 = (y0 >= 1.0f) ? 1.0f : 0.0f;
      float s1 = (y1 >= 1.0f) ? 1.0f : 0.0f;
      y0 = (s0 != 0.0f) ? 0.0f : y0;
      y1 = (s1 != 0.0f) ? 0.0f : y1;

      if (tpp >= t0) {
        int k = (tpp - t0) & 15;
        SB[wavei][0][wp][k] = s0;
        SB[wavei][1][wp][k] = s1;
        if (par == 1 && (k == 15 || tpp == t1 - 1)) {
          __syncthreads();
          int Kc  = k + 1;                  // 16 or 12 (both multiple of 4)
          int t0f = tpp - k;
#pragma unroll
          for (int o = 0; o < 2; ++o) {
            float* ob = outb + ((long)(o * HO + hp)) * (long)(WO * TO);
#pragma unroll
            for (int i = 0; i < 4; ++i) {
              int idx = (i << 6) + wp;
              int r   = idx >> 2;
              int c   = (idx & 3) << 2;
              if (c < Kc) {
                float4 vv;
                vv.x = SB[wavei][o][r][c + 0];
                vv.y = SB[wavei][o][r][c + 1];
                vv.z = SB[wavei][o][r][c + 2];
                vv.w = SB[wavei][o][r][c + 3];
                *reinterpret_cast<float4*>(ob + (long)r * TO + (t0f + c)) = vv;
              }
            }
          }
          __syncthreads();
        }
      }
    }
    q0 = q1; q1 = q2;
  }
}

// ---------------------------------------------------------------------------
extern "C" void kernel_launch(void* const* d_in, const int* in_sizes, int n_in,
                              void* d_out, int out_size, void* d_ws, size_t ws_size,
                              hipStream_t stream) {
  const float* x  = (const float*)d_in[0];
  const float* w1 = (const float*)d_in[1];
  const float* b1 = (const float*)d_in[2];
  const float* dw = (const float*)d_in[3];
  const float* db = (const float*)d_in[4];
  const float* cw = (const float*)d_in[5];
  const float* cb = (const float*)d_in[6];
  float* out = (float*)d_out;

  float* xT = (float*)d_ws;                                   // 22.94 MB
  signed char* d8 = (signed char*)d_ws + (size_t)B * CIN * T * HW * 4;  // +22.94 MB

  // 1) transpose x -> xT
  transpose_kernel<<<dim3(B * CIN * H * 6), dim3(256), 0, stream>>>(x, xT);
  // 2) conv1+relu+LIF1+delta -> d8 (8 chunks of 45, 512 blocks = 2/CU)
  convlif_kernel<<<dim3(B * 32 * 8), dim3(512), 0, stream>>>(xT, w1, b1, d8);
  // 3) deconv+relu+conv2+LIF2 -> out (25 chunks x 4-wave blocks, prefetch-2)
  stage2_kernel<<<dim3(B * 32 * 25), dim3(256), 0, stream>>>(d8, dw, db, cw, cb, out);
}

// Round 18
// 103.466 us; speedup vs baseline: 1.0919x; 1.0919x over previous
//
#include <hip/hip_runtime.h>

// Sizes (fixed for this problem)
constexpr int B  = 2,  CIN = 2,  H = 64, W = 64, T = 350;
constexpr int C1 = 8;                       // conv1 out channels
constexpr int TO = 700, HO = 128, WO = 64;
constexpr int HW = H * W;                   // 4096

#define DEC 0.05000000074505806f            // (float)(1.0 - 0.95)

// ---------------------------------------------------------------------------
// Kernel 0: transpose x [B,2,H,W,T] -> xT [B,2,T,H,W] so conv reads coalesce.
// ---------------------------------------------------------------------------
__global__ void __launch_bounds__(256) transpose_kernel(
    const float* __restrict__ x, float* __restrict__ xT) {
  __shared__ float tile[64][65];
  int bid   = blockIdx.x;
  int tTile = bid % 6;            // 6 tiles of 64 cover T=350
  int slice = bid / 6;            // (b*2+ci)*64 + h
  int h  = slice % H;
  int bc = slice / H;             // b*2+ci
  int t0 = tTile * 64;
  int tx = threadIdx.x & 63;
  int tz = threadIdx.x >> 6;      // 0..3

  const float* src = x + ((long)bc * H + h) * (long)(W * T);
#pragma unroll
  for (int i = 0; i < 16; ++i) {
    int w = tz * 16 + i;
    int t = t0 + tx;
    tile[w][tx] = (t < T) ? src[(long)w * T + t] : 0.0f;
  }
  __syncthreads();
  float* dst = xT + ((long)bc * T) * HW + h * 64;
#pragma unroll
  for (int i = 0; i < 16; ++i) {
    int tl = tz * 16 + i;
    int t  = t0 + tl;
    if (t < T) dst[(long)t * HW + tx] = tile[tx][tl];
  }
}

// ---------------------------------------------------------------------------
// async global->LDS, 16 bytes per lane (wave-uniform LDS base + lane*16)
// ---------------------------------------------------------------------------
__device__ __forceinline__ void gload_lds16(const float* g, float* l) {
  __builtin_amdgcn_global_load_lds(
      (const __attribute__((address_space(1))) unsigned int*)g,
      (__attribute__((address_space(3))) unsigned int*)l, 16, 0, 0);
}

// ---------------------------------------------------------------------------
// Kernel A: conv1(5x5 over T,H) + bias + relu + LIF1 + delta -> d8 int8
// d8 layout: [b][t][hw][ci]. 2-co-per-thread (r14 verbatim -- the 104us
// best). Block = 512 = (co-pair 0..3) x (h-sub 0..1) x (w 0..63); each
// thread's 10 ds_read_b32/step feed 100 FMAs. Grid = B x H/2 x 4 chunks =
// 256 blocks = 1/CU (512-thr blocks never pair on a CU -- measured r17:
// 2x74KB fits but occupancy stays 19%; don't chunk further).
// ---------------------------------------------------------------------------
__global__ void __launch_bounds__(512) convlif_kernel(
    const float* __restrict__ xT, const float* __restrict__ w1,
    const float* __restrict__ b1, signed char* __restrict__ d8) {
  __shared__ float buf[2][128 * 64];                    // 2 x 32 KiB
  __shared__ __align__(16) unsigned char st[10][1024];  // 10 KiB spikes
  const int tid = threadIdx.x;
  const int bid = blockIdx.x;
  const int chunk = bid & 3;
  const int rest  = bid >> 2;
  const int h2 = rest & 31;                 // h-pair index
  const int b  = rest >> 5;
  const int h0 = h2 * 2;
  const int w  = tid & 63;
  const int hs = (tid >> 6) & 1;            // wave h-sub
  const int cp = tid >> 7;                  // co-pair 0..3
  const int h  = h0 + hs;
  const int wid = tid >> 6;                 // wave id 0..7

  // chunk c of 4 (len 90,90,90,80): stored [90c, te); 15-step warm-up.
  const int tstore = chunk * 90;
  const int ts     = chunk ? tstore - 15 : 0;     // multiple of 5
  const int te     = tstore + 90 < T ? tstore + 90 : T;
  const int nsup   = (te - ts + 9) / 10;

  // Weights for co0=2cp, co1=2cp+1 (VGPR); zero taps with h+dh-2 OOB.
  float wt[2][2][5][5];
#pragma unroll
  for (int ci = 0; ci < 2; ++ci)
#pragma unroll
    for (int dh = 0; dh < 5; ++dh) {
      int hh = h + dh - 2;
      bool hv = (hh >= 0) && (hh < H);
#pragma unroll
      for (int dt = 0; dt < 5; ++dt) {
        wt[0][ci][dt][dh] = hv ? w1[(((cp*2+0) * 2 + ci) * 5 + dt) * 5 + dh] : 0.0f;
        wt[1][ci][dt][dh] = hv ? w1[(((cp*2+1) * 2 + ci) * 5 + dt) * 5 + dh] : 0.0f;
      }
    }
  float bias0 = b1[cp*2], bias1 = b1[cp*2+1];

  // Staging descriptors: 4 issues x 32 rows; row r = j*12 + ci*6 + dhh,
  // dhh in [0,6) covering h rows h0-2..h0+3 (union of both h-subs).
  int cdesc[4];
#pragma unroll
  for (int i = 0; i < 4; ++i) {
    int r = (tid >> 4) + 32 * i;
    if (r > 119) r = 119;                   // clamp SOURCE; dest rows <=127 ok
    int j   = r / 12;
    int rem = r - j * 12;
    int ci  = rem / 6;
    int dhh = rem - ci * 6;
    int hh = h0 + dhh - 2;
    int hc = hh < 0 ? 0 : (hh > H - 1 ? H - 1 : hh);
    cdesc[i] = (((b * 2 + ci) * T) * HW + hc * 64 + (tid & 15) * 4) | (j << 27);
  }

  // Prologue: stage buf[0] (taus ts+3 .. ts+12).
#pragma unroll
  for (int i = 0; i < 4; ++i) {
    int tau = ts + 3 + (cdesc[i] >> 27);
    if (tau > T - 1) tau = T - 1;
    gload_lds16(xT + (long)(cdesc[i] & 0x07ffffff) + (long)tau * HW,
                &buf[0][(i * 32 + wid * 4) * 64]);
  }

  // Window init (taus ts-2..ts+2) from global; slot = tau % 5 (ts%5==0).
  float win[2][5][5];
#pragma unroll
  for (int ci = 0; ci < 2; ++ci)
#pragma unroll
    for (int dh = 0; dh < 5; ++dh) {
      int hh = h + dh - 2;
      int hc = hh < 0 ? 0 : (hh > H - 1 ? H - 1 : hh);
      const float* bp = xT + ((long)((b * 2 + ci) * T)) * HW + hc * 64 + w;
      win[ci][dh][3] = (ts >= 2) ? bp[(long)(ts - 2) * HW] : 0.0f;
      win[ci][dh][4] = (ts >= 1) ? bp[(long)(ts - 1) * HW] : 0.0f;
      win[ci][dh][0] = bp[(long)(ts + 0) * HW];
      win[ci][dh][1] = bp[(long)(ts + 1) * HW];
      win[ci][dh][2] = bp[(long)(ts + 2) * HW];
    }

  asm volatile("s_waitcnt vmcnt(0)" ::: "memory");
  __builtin_amdgcn_s_barrier();
  asm volatile("" ::: "memory");

  signed char* const d8row = d8 + ((long)(b * T)) * (HW * C1) + h0 * 512;
  const int stw = ((hs * 64 + w) * 8 + cp * 2) >> 1;   // ushort index in row

  float y0 = 0.0f, y1 = 0.0f, sp0 = 0.0f, sp1 = 0.0f;
  for (int k = 0; k < nsup; ++k) {
    // barrier1: publish st writes of superstep k-1; next-buf readers done.
    asm volatile("s_waitcnt lgkmcnt(0)" ::: "memory");
    __builtin_amdgcn_s_barrier();
    asm volatile("" ::: "memory");

    // Flush superstep k-1 spikes (stores issued BEFORE staging loads so
    // vmcnt(4) drains them along with buffer-k loads).
    if (k > 0) {
      int tb = ts + 10 * (k - 1);
#pragma unroll
      for (int i = 0; i < 2; ++i) {
        int slot = tid + i * 512;
        if (slot < 640) {
          int u = slot >> 6;
          int c = (slot & 63) * 16;
          int t = tb + u;
          if (t >= tstore && t < te) {
            uint4 v = *reinterpret_cast<const uint4*>(&st[u][c]);
            *reinterpret_cast<uint4*>(d8row + (long)t * (HW * C1) + c) = v;
          }
        }
      }
    }

    if (k + 1 < nsup) {
      int bs = ts + 3 + 10 * (k + 1);
      float* nb = &buf[(k + 1) & 1][0];
#pragma unroll
      for (int i = 0; i < 4; ++i) {
        int tau = bs + (cdesc[i] >> 27);
        if (tau > T - 1) tau = T - 1;
        gload_lds16(xT + (long)(cdesc[i] & 0x07ffffff) + (long)tau * HW,
                    nb + (i * 32 + wid * 4) * 64);
      }
      asm volatile("s_waitcnt vmcnt(4)" ::: "memory");  // buf[k&1]+stores done
    } else {
      asm volatile("s_waitcnt vmcnt(0)" ::: "memory");
    }
    asm volatile("s_waitcnt lgkmcnt(0)" ::: "memory");
    __builtin_amdgcn_s_barrier();           // barrier2: buf[k&1] ready, st free
    asm volatile("" ::: "memory");

    float* lb = &buf[k & 1][0];
    {
      // zero rows whose tau >= T (final supersteps of last chunk only)
      int bufstart = ts + 3 + 10 * k;
      int rz0 = (T - bufstart) * 12;
      if (rz0 < 120) {
        if (rz0 < 0) rz0 = 0;
        for (int r = rz0 + wid; r < 120; r += 8) lb[r * 64 + w] = 0.0f;
        asm volatile("s_waitcnt lgkmcnt(0)" ::: "memory");
        __builtin_amdgcn_s_barrier();
        asm volatile("" ::: "memory");
      }
    }

    const int t0s = ts + 10 * k;
    for (int jj = 0; jj < 2; ++jj) {
#pragma unroll
      for (int u = 0; u < 5; ++u) {
        const int j5 = jj * 5;
        int t = t0s + j5 + u;
        float a0q0 = 0.f, a0q1 = 0.f, a0q2 = 0.f, a0q3 = 0.f;
        float a1q0 = 0.f, a1q1 = 0.f, a1q2 = 0.f, a1q3 = 0.f;
#pragma unroll
        for (int ci = 0; ci < 2; ++ci)
#pragma unroll
          for (int dt = 0; dt < 5; ++dt) {
            const int slot = (u + dt + 3) % 5;
#pragma unroll
            for (int dh = 0; dh < 5; ++dh) {
              const int q = (ci * 25 + dt * 5 + dh) & 3;
              float tap = win[ci][dh][slot];
              float p0 = tap * wt[0][ci][dt][dh];
              float p1 = tap * wt[1][ci][dt][dh];
              if (q == 0)      { a0q0 += p0; a1q0 += p1; }
              else if (q == 1) { a0q1 += p0; a1q1 += p1; }
              else if (q == 2) { a0q2 += p0; a1q2 += p1; }
              else             { a0q3 += p0; a1q3 += p1; }
            }
          }
        float a0 = fmaxf(((a0q0 + a0q1) + (a0q2 + a0q3)) + bias0, 0.0f);
        float a1 = fmaxf(((a1q0 + a1q1) + (a1q2 + a1q3)) + bias1, 0.0f);
        y0 = fmaf(DEC, y0, a0);
        y1 = fmaf(DEC, y1, a1);
        float s0 = (y0 >= 1.0f) ? 1.0f : 0.0f;
        float s1 = (y1 >= 1.0f) ? 1.0f : 0.0f;
        int d0 = (int)(s0 - sp0) & 0xff;
        int d1 = (int)(s1 - sp1) & 0xff;
        unsigned short val = (unsigned short)(d0 | (d1 << 8));
        if (t == 0) val = 0;
        reinterpret_cast<unsigned short*>(&st[j5 + u][0])[stw] = val;
        sp0 = s0; sp1 = s1;
        y0 = (s0 != 0.0f) ? 0.0f : y0;
        y1 = (s1 != 0.0f) ? 0.0f : y1;
        // slide: tau = t+3 at row ((j5+u)*12 + ci*6 + dh + hs)
        const int slot2 = (u + 3) % 5;
#pragma unroll
        for (int ci = 0; ci < 2; ++ci)
#pragma unroll
          for (int dh = 0; dh < 5; ++dh)
            win[ci][dh][slot2] =
                lb[((j5 + u) * 12 + ci * 6 + dh + hs) * 64 + w];
      }
    }
  }

  // Epilogue flush: last superstep's spikes.
  asm volatile("s_waitcnt lgkmcnt(0)" ::: "memory");
  __builtin_amdgcn_s_barrier();
  asm volatile("" ::: "memory");
  {
    int tb = ts + 10 * (nsup - 1);
#pragma unroll
    for (int i = 0; i < 2; ++i) {
      int slot = tid + i * 512;
      if (slot < 640) {
        int u = slot >> 6;
        int c = (slot & 63) * 16;
        int t = tb + u;
        if (t >= tstore && t < te) {
          uint4 v = *reinterpret_cast<const uint4*>(&st[u][c]);
          *reinterpret_cast<uint4*>(d8row + (long)t * (HW * C1) + c) = v;
        }
      }
    }
  }
}

// ---------------------------------------------------------------------------
// Kernel B: deconv(2x2,s2) + bias + relu + conv2(1x1) + LIF2 -> out
// d8 [b][t][hw][ci]: one 8B uint2 load per pair-step.
// r14 structure (16 chunks of 44, 64-thr blocks -- part of the 104us best)
// + ONE change: prefetch depth 2 (three uint2 in flight) to cover the full
// ~200-400cyc L2 latency instead of ~100cyc.
// ---------------------------------------------------------------------------
__global__ void __launch_bounds__(64) stage2_kernel(
    const signed char* __restrict__ d8, const float* __restrict__ dw,
    const float* __restrict__ db, const float* __restrict__ cw,
    const float* __restrict__ cb, float* __restrict__ out) {
  __shared__ float SB[2][64][17];
  int bid   = blockIdx.x;
  int chunk = bid & 15;           // 16 chunks over T'=700
  int rest  = bid >> 4;
  int hp = rest & 127;            // h'
  int b  = rest >> 7;
  int wp = threadIdx.x;           // w'

  int h  = hp >> 1;
  int kh = 1 - (hp & 1);

  float dwk0[2][8], dwk1[2][8];
#pragma unroll
  for (int c = 0; c < 2; ++c)
#pragma unroll
    for (int ci = 0; ci < 8; ++ci) {
      dwk0[c][ci] = dw[((c * 8 + ci) * 2 + 0) * 2 + kh];
      dwk1[c][ci] = dw[((c * 8 + ci) * 2 + 1) * 2 + kh];
    }
  float db0 = db[0], db1 = db[1];
  float cw00 = cw[0], cw01 = cw[1], cw10 = cw[2], cw11 = cw[3];
  float cb0 = cb[0], cb1 = cb[1];

  int t0 = chunk * 44;
  int t1 = (t0 + 44 < TO) ? t0 + 44 : TO;   // last chunk: 40
  int tw = (t0 - 16 > 0) ? t0 - 16 : 0;     // 16-step LIF2 warm-up (even)

  const signed char* dbase = d8 + (((long)b * T) * HW + h * 64 + wp) * C1;
  const long tstride = (long)HW * C1;       // bytes per t
  float* outb = out + ((long)b * 2 * HO) * (long)(WO * TO);

  // Prefetch pipeline, depth 2 (q0 = current, q1/q2 in flight).
  auto ldq = [&](int tp) -> uint2 {
    int t = (tp < t1) ? (tp >> 1) : ((t1 - 1) >> 1);
    return *reinterpret_cast<const uint2*>(dbase + (long)t * tstride);
  };
  uint2 q0 = ldq(tw);
  uint2 q1 = ldq(tw + 2);

  float y0 = 0.0f, y1 = 0.0f;
  for (int tp = tw; tp < t1; tp += 2) {
    uint2 q2 = ldq(tp + 4);

    float dv[8];
#pragma unroll
    for (int ci = 0; ci < 4; ++ci) {
      dv[ci]     = (float)(signed char)((q0.x >> (8 * ci)) & 0xff);
      dv[ci + 4] = (float)(signed char)((q0.y >> (8 * ci)) & 0xff);
    }

#pragma unroll
    for (int par = 0; par < 2; ++par) {     // par=0: tp (kt=1), par=1: tp+1 (kt=0)
      int tpp = tp + par;
      float v0 = db0, v1 = db1;
      if (par == 0) {
#pragma unroll
        for (int ci = 0; ci < 8; ++ci) {
          v0 = fmaf(dv[ci], dwk1[0][ci], v0);
          v1 = fmaf(dv[ci], dwk1[1][ci], v1);
        }
      } else {
#pragma unroll
        for (int ci = 0; ci < 8; ++ci) {
          v0 = fmaf(dv[ci], dwk0[0][ci], v0);
          v1 = fmaf(dv[ci], dwk0[1][ci], v1);
        }
      }
      v0 = fmaxf(v0, 0.0f);
      v1 = fmaxf(v1, 0.0f);
      float u0 = fmaf(cw00, v0, fmaf(cw01, v1, cb0));
      float u1 = fmaf(cw10, v0, fmaf(cw11, v1, cb1));
      y0 = fmaf(DEC, y0, u0);
      y1 = fmaf(DEC, y1, u1);
      float s0 = (y0 >= 1.0f) ? 1.0f : 0.0f;
      float s1 = (y1 >= 1.0f) ? 1.0f : 0.0f;
      y0 = (s0 != 0.0f) ? 0.0f : y0;
      y1 = (s1 != 0.0f) ? 0.0f : y1;

      if (tpp >= t0) {
        int k = (tpp - t0) & 15;
        SB[0][wp][k] = s0;
        SB[1][wp][k] = s1;
        if (par == 1 && (k == 15 || tpp == t1 - 1)) {
          __syncthreads();
          int Kc  = k + 1;                  // 16 or a multiple of 4
          int t0f = tpp - k;
#pragma unroll
          for (int o = 0; o < 2; ++o) {
            float* ob = outb + ((long)(o * HO + hp)) * (long)(WO * TO);
#pragma unroll
            for (int i = 0; i < 4; ++i) {
              int idx = (i << 6) + wp;
              int r   = idx >> 2;
              int c   = (idx & 3) << 2;
              if (c < Kc) {
                float4 vv;
                vv.x = SB[o][r][c + 0];
                vv.y = SB[o][r][c + 1];
                vv.z = SB[o][r][c + 2];
                vv.w = SB[o][r][c + 3];
                *reinterpret_cast<float4*>(ob + (long)r * TO + (t0f + c)) = vv;
              }
            }
          }
          __syncthreads();
        }
      }
    }
    q0 = q1; q1 = q2;
  }
}

// ---------------------------------------------------------------------------
extern "C" void kernel_launch(void* const* d_in, const int* in_sizes, int n_in,
                              void* d_out, int out_size, void* d_ws, size_t ws_size,
                              hipStream_t stream) {
  const float* x  = (const float*)d_in[0];
  const float* w1 = (const float*)d_in[1];
  const float* b1 = (const float*)d_in[2];
  const float* dw = (const float*)d_in[3];
  const float* db = (const float*)d_in[4];
  const float* cw = (const float*)d_in[5];
  const float* cb = (const float*)d_in[6];
  float* out = (float*)d_out;

  float* xT = (float*)d_ws;                                   // 22.94 MB
  signed char* d8 = (signed char*)d_ws + (size_t)B * CIN * T * HW * 4;  // +22.94 MB

  // 1) transpose x -> xT
  transpose_kernel<<<dim3(B * CIN * H * 6), dim3(256), 0, stream>>>(x, xT);
  // 2) conv1+relu+LIF1+delta -> d8 (2-co/thread, 4 chunks, 256 blocks)
  convlif_kernel<<<dim3(B * 32 * 4), dim3(512), 0, stream>>>(xT, w1, b1, d8);
  // 3) deconv+relu+conv2+LIF2 -> out (16 chunks, 64-thr blocks, prefetch-2)
  stage2_kernel<<<dim3(B * HO * 16), dim3(64), 0, stream>>>(d8, dw, db, cw, cb, out);
}

// Round 19
// 102.931 us; speedup vs baseline: 1.0975x; 1.0052x over previous
//
#include <hip/hip_runtime.h>

// Sizes (fixed for this problem)
constexpr int B  = 2,  CIN = 2,  H = 64, W = 64, T = 350;
constexpr int C1 = 8;                       // conv1 out channels
constexpr int TO = 700, HO = 128, WO = 64;
constexpr int HW = H * W;                   // 4096

#define DEC 0.05000000074505806f            // (float)(1.0 - 0.95)

// ---------------------------------------------------------------------------
// Kernel 0: transpose x [B,2,H,W,T] -> xT [B,2,T,H,W] so conv reads coalesce.
// ---------------------------------------------------------------------------
__global__ void __launch_bounds__(256) transpose_kernel(
    const float* __restrict__ x, float* __restrict__ xT) {
  __shared__ float tile[64][65];
  int bid   = blockIdx.x;
  int tTile = bid % 6;            // 6 tiles of 64 cover T=350
  int slice = bid / 6;            // (b*2+ci)*64 + h
  int h  = slice % H;
  int bc = slice / H;             // b*2+ci
  int t0 = tTile * 64;
  int tx = threadIdx.x & 63;
  int tz = threadIdx.x >> 6;      // 0..3

  const float* src = x + ((long)bc * H + h) * (long)(W * T);
#pragma unroll
  for (int i = 0; i < 16; ++i) {
    int w = tz * 16 + i;
    int t = t0 + tx;
    tile[w][tx] = (t < T) ? src[(long)w * T + t] : 0.0f;
  }
  __syncthreads();
  float* dst = xT + ((long)bc * T) * HW + h * 64;
#pragma unroll
  for (int i = 0; i < 16; ++i) {
    int tl = tz * 16 + i;
    int t  = t0 + tl;
    if (t < T) dst[(long)t * HW + tx] = tile[tx][tl];
  }
}

// ---------------------------------------------------------------------------
// async global->LDS, 16 bytes per lane (wave-uniform LDS base + lane*16)
// ---------------------------------------------------------------------------
__device__ __forceinline__ void gload_lds16(const float* g, float* l) {
  __builtin_amdgcn_global_load_lds(
      (const __attribute__((address_space(1))) unsigned int*)g,
      (__attribute__((address_space(3))) unsigned int*)l, 16, 0, 0);
}

// ---------------------------------------------------------------------------
// Kernel A: conv1(5x5 over T,H) + bias + relu + LIF1 + delta -> d8 int8
// d8 layout: [b][t][hw][ci]. 2-co-per-thread compute (r14 economics).
// CHANGE r19: 256-thread blocks (cp 0..3 x w 0..63), ONE h per block.
// 512-thr blocks never pair on a CU (r17 measured); 256-thr blocks do
// (stage2/transpose evidence). LDS = 2 x 28KB input dbuf (112 rows:
// 100 data + 12 pad, staged by 7 gload issues x 16 rows) + 5KB st
// = 62.5KB -> 2 blocks/CU. Grid = B x H x 4 chunks = 512 = 2/CU; the two
// blocks' barrier/vmcnt stalls de-correlate and fill the SIMDs.
// ---------------------------------------------------------------------------
__global__ void __launch_bounds__(256) convlif_kernel(
    const float* __restrict__ xT, const float* __restrict__ w1,
    const float* __restrict__ b1, signed char* __restrict__ d8) {
  __shared__ float buf[2][112 * 64];                    // 2 x 28 KiB
  __shared__ __align__(16) unsigned char st[10][512];   // 5 KiB spikes
  const int tid = threadIdx.x;
  const int bid = blockIdx.x;
  const int chunk = bid & 3;
  const int rest  = bid >> 2;
  const int h = rest & 63;
  const int b = rest >> 6;
  const int w  = tid & 63;
  const int cp = tid >> 6;                  // co-pair == wave id 0..3
  const int wid = tid >> 6;

  // chunk c of 4 (len 90,90,90,80): stored [90c, te); 15-step warm-up.
  const int tstore = chunk * 90;
  const int ts     = chunk ? tstore - 15 : 0;     // multiple of 5
  const int te     = tstore + 90 < T ? tstore + 90 : T;
  const int nsup   = (te - ts + 9) / 10;

  // Weights for co0=2cp, co1=2cp+1 (VGPR); zero taps with h+dh-2 OOB.
  float wt[2][2][5][5];
#pragma unroll
  for (int ci = 0; ci < 2; ++ci)
#pragma unroll
    for (int dh = 0; dh < 5; ++dh) {
      int hh = h + dh - 2;
      bool hv = (hh >= 0) && (hh < H);
#pragma unroll
      for (int dt = 0; dt < 5; ++dt) {
        wt[0][ci][dt][dh] = hv ? w1[(((cp*2+0) * 2 + ci) * 5 + dt) * 5 + dh] : 0.0f;
        wt[1][ci][dt][dh] = hv ? w1[(((cp*2+1) * 2 + ci) * 5 + dt) * 5 + dh] : 0.0f;
      }
    }
  float bias0 = b1[cp*2], bias1 = b1[cp*2+1];

  // Staging descriptors: 7 issues x 16 rows; row r = j*10 + ci*5 + dh,
  // j in [0,10) = tau offset. Rows 100..111 are in-buffer pad (r6 lesson).
  int cdesc[7];
#pragma unroll
  for (int i = 0; i < 7; ++i) {
    int r = (tid >> 4) + 16 * i;
    if (r > 99) r = 99;                     // clamp SOURCE only
    int j   = r / 10;
    int rem = r - j * 10;
    int ci  = rem / 5;
    int dh  = rem - ci * 5;
    int hh = h + dh - 2;
    int hc = hh < 0 ? 0 : (hh > H - 1 ? H - 1 : hh);
    cdesc[i] = (((b * 2 + ci) * T) * HW + hc * 64 + (tid & 15) * 4) | (j << 27);
  }

  // Prologue: stage buf[0] (taus ts+3 .. ts+12).
#pragma unroll
  for (int i = 0; i < 7; ++i) {
    int tau = ts + 3 + (cdesc[i] >> 27);
    if (tau > T - 1) tau = T - 1;
    gload_lds16(xT + (long)(cdesc[i] & 0x07ffffff) + (long)tau * HW,
                &buf[0][(i * 16 + wid * 4) * 64]);
  }

  // Window init (taus ts-2..ts+2) from global; slot = tau % 5 (ts%5==0).
  float win[2][5][5];
#pragma unroll
  for (int ci = 0; ci < 2; ++ci)
#pragma unroll
    for (int dh = 0; dh < 5; ++dh) {
      int hh = h + dh - 2;
      int hc = hh < 0 ? 0 : (hh > H - 1 ? H - 1 : hh);
      const float* bp = xT + ((long)((b * 2 + ci) * T)) * HW + hc * 64 + w;
      win[ci][dh][3] = (ts >= 2) ? bp[(long)(ts - 2) * HW] : 0.0f;
      win[ci][dh][4] = (ts >= 1) ? bp[(long)(ts - 1) * HW] : 0.0f;
      win[ci][dh][0] = bp[(long)(ts + 0) * HW];
      win[ci][dh][1] = bp[(long)(ts + 1) * HW];
      win[ci][dh][2] = bp[(long)(ts + 2) * HW];
    }

  asm volatile("s_waitcnt vmcnt(0)" ::: "memory");
  __builtin_amdgcn_s_barrier();
  asm volatile("" ::: "memory");

  signed char* const d8row = d8 + ((long)(b * T)) * (HW * C1) + h * 512;
  const int stw = w * 4 + cp;               // ushort slot in 512B st row

  float y0 = 0.0f, y1 = 0.0f, sp0 = 0.0f, sp1 = 0.0f;
  for (int k = 0; k < nsup; ++k) {
    // barrier1: publish st writes of superstep k-1; next-buf readers done.
    asm volatile("s_waitcnt lgkmcnt(0)" ::: "memory");
    __builtin_amdgcn_s_barrier();
    asm volatile("" ::: "memory");

    // Flush superstep k-1 spikes (stores issued BEFORE staging loads so
    // vmcnt(7) drains them along with buffer-k loads). 320 uint4 slots.
    if (k > 0) {
      int tb = ts + 10 * (k - 1);
#pragma unroll
      for (int i = 0; i < 2; ++i) {
        int slot = tid + i * 256;
        if (slot < 320) {
          int u = slot >> 5;
          int c = (slot & 31) * 16;
          int t = tb + u;
          if (t >= tstore && t < te) {
            uint4 v = *reinterpret_cast<const uint4*>(&st[u][c]);
            *reinterpret_cast<uint4*>(d8row + (long)t * (HW * C1) + c) = v;
          }
        }
      }
    }

    if (k + 1 < nsup) {
      int bs = ts + 3 + 10 * (k + 1);
      float* nb = &buf[(k + 1) & 1][0];
#pragma unroll
      for (int i = 0; i < 7; ++i) {
        int tau = bs + (cdesc[i] >> 27);
        if (tau > T - 1) tau = T - 1;
        gload_lds16(xT + (long)(cdesc[i] & 0x07ffffff) + (long)tau * HW,
                    nb + (i * 16 + wid * 4) * 64);
      }
      asm volatile("s_waitcnt vmcnt(7)" ::: "memory");  // buf[k&1]+stores done
    } else {
      asm volatile("s_waitcnt vmcnt(0)" ::: "memory");
    }
    asm volatile("s_waitcnt lgkmcnt(0)" ::: "memory");
    __builtin_amdgcn_s_barrier();           // barrier2: buf[k&1] ready, st free
    asm volatile("" ::: "memory");

    float* lb = &buf[k & 1][0];
    {
      // zero rows whose tau >= T (final supersteps of last chunk only)
      int bufstart = ts + 3 + 10 * k;
      int rz0 = (T - bufstart) * 10;
      if (rz0 < 100) {
        if (rz0 < 0) rz0 = 0;
        for (int r = rz0 + wid; r < 100; r += 4) lb[r * 64 + w] = 0.0f;
        asm volatile("s_waitcnt lgkmcnt(0)" ::: "memory");
        __builtin_amdgcn_s_barrier();
        asm volatile("" ::: "memory");
      }
    }

    const int t0s = ts + 10 * k;
    for (int jj = 0; jj < 2; ++jj) {
#pragma unroll
      for (int u = 0; u < 5; ++u) {
        const int j5 = jj * 5;
        int t = t0s + j5 + u;
        float a0q0 = 0.f, a0q1 = 0.f, a0q2 = 0.f, a0q3 = 0.f;
        float a1q0 = 0.f, a1q1 = 0.f, a1q2 = 0.f, a1q3 = 0.f;
#pragma unroll
        for (int ci = 0; ci < 2; ++ci)
#pragma unroll
          for (int dt = 0; dt < 5; ++dt) {
            const int slot = (u + dt + 3) % 5;
#pragma unroll
            for (int dh = 0; dh < 5; ++dh) {
              const int q = (ci * 25 + dt * 5 + dh) & 3;
              float tap = win[ci][dh][slot];
              float p0 = tap * wt[0][ci][dt][dh];
              float p1 = tap * wt[1][ci][dt][dh];
              if (q == 0)      { a0q0 += p0; a1q0 += p1; }
              else if (q == 1) { a0q1 += p0; a1q1 += p1; }
              else if (q == 2) { a0q2 += p0; a1q2 += p1; }
              else             { a0q3 += p0; a1q3 += p1; }
            }
          }
        float a0 = fmaxf(((a0q0 + a0q1) + (a0q2 + a0q3)) + bias0, 0.0f);
        float a1 = fmaxf(((a1q0 + a1q1) + (a1q2 + a1q3)) + bias1, 0.0f);
        y0 = fmaf(DEC, y0, a0);
        y1 = fmaf(DEC, y1, a1);
        float s0 = (y0 >= 1.0f) ? 1.0f : 0.0f;
        float s1 = (y1 >= 1.0f) ? 1.0f : 0.0f;
        int d0 = (int)(s0 - sp0) & 0xff;
        int d1 = (int)(s1 - sp1) & 0xff;
        unsigned short val = (unsigned short)(d0 | (d1 << 8));
        if (t == 0) val = 0;
        reinterpret_cast<unsigned short*>(&st[j5 + u][0])[stw] = val;
        sp0 = s0; sp1 = s1;
        y0 = (s0 != 0.0f) ? 0.0f : y0;
        y1 = (s1 != 0.0f) ? 0.0f : y1;
        // slide: tau = t+3 at row ((j5+u)*10 + ci*5 + dh)
        const int slot2 = (u + 3) % 5;
#pragma unroll
        for (int ci = 0; ci < 2; ++ci)
#pragma unroll
          for (int dh = 0; dh < 5; ++dh)
            win[ci][dh][slot2] =
                lb[((j5 + u) * 10 + ci * 5 + dh) * 64 + w];
      }
    }
  }

  // Epilogue flush: last superstep's spikes.
  asm volatile("s_waitcnt lgkmcnt(0)" ::: "memory");
  __builtin_amdgcn_s_barrier();
  asm volatile("" ::: "memory");
  {
    int tb = ts + 10 * (nsup - 1);
#pragma unroll
    for (int i = 0; i < 2; ++i) {
      int slot = tid + i * 256;
      if (slot < 320) {
        int u = slot >> 5;
        int c = (slot & 31) * 16;
        int t = tb + u;
        if (t >= tstore && t < te) {
          uint4 v = *reinterpret_cast<const uint4*>(&st[u][c]);
          *reinterpret_cast<uint4*>(d8row + (long)t * (HW * C1) + c) = v;
        }
      }
    }
  }
}

// ---------------------------------------------------------------------------
// Kernel B: deconv(2x2,s2) + bias + relu + conv2(1x1) + LIF2 -> out
// d8 [b][t][hw][ci]: one 8B uint2 load per pair-step, prefetch depth 2.
// (r18 verbatim -- current best config)
// ---------------------------------------------------------------------------
__global__ void __launch_bounds__(64) stage2_kernel(
    const signed char* __restrict__ d8, const float* __restrict__ dw,
    const float* __restrict__ db, const float* __restrict__ cw,
    const float* __restrict__ cb, float* __restrict__ out) {
  __shared__ float SB[2][64][17];
  int bid   = blockIdx.x;
  int chunk = bid & 15;           // 16 chunks over T'=700
  int rest  = bid >> 4;
  int hp = rest & 127;            // h'
  int b  = rest >> 7;
  int wp = threadIdx.x;           // w'

  int h  = hp >> 1;
  int kh = 1 - (hp & 1);

  float dwk0[2][8], dwk1[2][8];
#pragma unroll
  for (int c = 0; c < 2; ++c)
#pragma unroll
    for (int ci = 0; ci < 8; ++ci) {
      dwk0[c][ci] = dw[((c * 8 + ci) * 2 + 0) * 2 + kh];
      dwk1[c][ci] = dw[((c * 8 + ci) * 2 + 1) * 2 + kh];
    }
  float db0 = db[0], db1 = db[1];
  float cw00 = cw[0], cw01 = cw[1], cw10 = cw[2], cw11 = cw[3];
  float cb0 = cb[0], cb1 = cb[1];

  int t0 = chunk * 44;
  int t1 = (t0 + 44 < TO) ? t0 + 44 : TO;   // last chunk: 40
  int tw = (t0 - 16 > 0) ? t0 - 16 : 0;     // 16-step LIF2 warm-up (even)

  const signed char* dbase = d8 + (((long)b * T) * HW + h * 64 + wp) * C1;
  const long tstride = (long)HW * C1;       // bytes per t
  float* outb = out + ((long)b * 2 * HO) * (long)(WO * TO);

  // Prefetch pipeline, depth 2 (q0 = current, q1/q2 in flight).
  auto ldq = [&](int tp) -> uint2 {
    int t = (tp < t1) ? (tp >> 1) : ((t1 - 1) >> 1);
    return *reinterpret_cast<const uint2*>(dbase + (long)t * tstride);
  };
  uint2 q0 = ldq(tw);
  uint2 q1 = ldq(tw + 2);

  float y0 = 0.0f, y1 = 0.0f;
  for (int tp = tw; tp < t1; tp += 2) {
    uint2 q2 = ldq(tp + 4);

    float dv[8];
#pragma unroll
    for (int ci = 0; ci < 4; ++ci) {
      dv[ci]     = (float)(signed char)((q0.x >> (8 * ci)) & 0xff);
      dv[ci + 4] = (float)(signed char)((q0.y >> (8 * ci)) & 0xff);
    }

#pragma unroll
    for (int par = 0; par < 2; ++par) {     // par=0: tp (kt=1), par=1: tp+1 (kt=0)
      int tpp = tp + par;
      float v0 = db0, v1 = db1;
      if (par == 0) {
#pragma unroll
        for (int ci = 0; ci < 8; ++ci) {
          v0 = fmaf(dv[ci], dwk1[0][ci], v0);
          v1 = fmaf(dv[ci], dwk1[1][ci], v1);
        }
      } else {
#pragma unroll
        for (int ci = 0; ci < 8; ++ci) {
          v0 = fmaf(dv[ci], dwk0[0][ci], v0);
          v1 = fmaf(dv[ci], dwk0[1][ci], v1);
        }
      }
      v0 = fmaxf(v0, 0.0f);
      v1 = fmaxf(v1, 0.0f);
      float u0 = fmaf(cw00, v0, fmaf(cw01, v1, cb0));
      float u1 = fmaf(cw10, v0, fmaf(cw11, v1, cb1));
      y0 = fmaf(DEC, y0, u0);
      y1 = fmaf(DEC, y1, u1);
      float s0 = (y0 >= 1.0f) ? 1.0f : 0.0f;
      float s1 = (y1 >= 1.0f) ? 1.0f : 0.0f;
      y0 = (s0 != 0.0f) ? 0.0f : y0;
      y1 = (s1 != 0.0f) ? 0.0f : y1;

      if (tpp >= t0) {
        int k = (tpp - t0) & 15;
        SB[0][wp][k] = s0;
        SB[1][wp][k] = s1;
        if (par == 1 && (k == 15 || tpp == t1 - 1)) {
          __syncthreads();
          int Kc  = k + 1;                  // 16 or a multiple of 4
          int t0f = tpp - k;
#pragma unroll
          for (int o = 0; o < 2; ++o) {
            float* ob = outb + ((long)(o * HO + hp)) * (long)(WO * TO);
#pragma unroll
            for (int i = 0; i < 4; ++i) {
              int idx = (i << 6) + wp;
              int r   = idx >> 2;
              int c   = (idx & 3) << 2;
              if (c < Kc) {
                float4 vv;
                vv.x = SB[o][r][c + 0];
                vv.y = SB[o][r][c + 1];
                vv.z = SB[o][r][c + 2];
                vv.w = SB[o][r][c + 3];
                *reinterpret_cast<float4*>(ob + (long)r * TO + (t0f + c)) = vv;
              }
            }
          }
          __syncthreads();
        }
      }
    }
    q0 = q1; q1 = q2;
  }
}

// ---------------------------------------------------------------------------
extern "C" void kernel_launch(void* const* d_in, const int* in_sizes, int n_in,
                              void* d_out, int out_size, void* d_ws, size_t ws_size,
                              hipStream_t stream) {
  const float* x  = (const float*)d_in[0];
  const float* w1 = (const float*)d_in[1];
  const float* b1 = (const float*)d_in[2];
  const float* dw = (const float*)d_in[3];
  const float* db = (const float*)d_in[4];
  const float* cw = (const float*)d_in[5];
  const float* cb = (const float*)d_in[6];
  float* out = (float*)d_out;

  float* xT = (float*)d_ws;                                   // 22.94 MB
  signed char* d8 = (signed char*)d_ws + (size_t)B * CIN * T * HW * 4;  // +22.94 MB

  // 1) transpose x -> xT
  transpose_kernel<<<dim3(B * CIN * H * 6), dim3(256), 0, stream>>>(x, xT);
  // 2) conv1+relu+LIF1+delta -> d8 (256-thr blocks, 1 h/block, 2 blocks/CU)
  convlif_kernel<<<dim3(B * H * 4), dim3(256), 0, stream>>>(xT, w1, b1, d8);
  // 3) deconv+relu+conv2+LIF2 -> out (16 chunks, 64-thr blocks, prefetch-2)
  stage2_kernel<<<dim3(B * HO * 16), dim3(64), 0, stream>>>(d8, dw, db, cw, cb, out);
}